// Round 2
// baseline (153.870 us; speedup 1.0000x reference)
//
#include <hip/hip_runtime.h>
#include <hip/hip_bf16.h>

// Problem constants (from reference)
#define NUM_NEURONS 32768
#define INPUT_SIZE  8192
#define BATCH       512

// ---------------------------------------------------------------------------
// Kernel A: per-neuron softmax over 16 gate weights -> 4 affine coefficients.
// Every logic op is affine in {1, a, b, ab}:
//   out = C0 + Ca*a + Cb*b + Cab*a*b
// ---------------------------------------------------------------------------
__global__ __launch_bounds__(256) void logic_coeff_kernel(
    const float* __restrict__ gw, float4* __restrict__ coeffs)
{
    const int n = blockIdx.x * 256 + threadIdx.x;
    if (n >= NUM_NEURONS) return;
    const float* g = gw + (size_t)n * 16;

    float w[16];
#pragma unroll
    for (int i = 0; i < 16; i += 4) {
        float4 v = *reinterpret_cast<const float4*>(g + i);
        w[i+0] = v.x; w[i+1] = v.y; w[i+2] = v.z; w[i+3] = v.w;
    }
    float m = w[0];
#pragma unroll
    for (int i = 1; i < 16; ++i) m = fmaxf(m, w[i]);
    float s = 0.f;
#pragma unroll
    for (int i = 0; i < 16; ++i) { w[i] = expf(w[i] - m); s += w[i]; }
    const float inv = 1.0f / s;

    const float C0  = (w[8] + w[9] + w[10] + w[11] + w[12] + w[13] + w[14] + w[15]) * inv;
    const float Ca  = (w[2] + w[3] + w[6] + w[7] - w[8] - w[9] - w[12] - w[13]) * inv;
    const float Cb  = (w[4] + w[5] + w[6] + w[7] - w[8] - w[9] - w[10] - w[11]) * inv;
    const float Cab = (w[1] - w[2] - w[4] - 2.f*w[6] - w[7]
                       + w[8] + 2.f*w[9] + w[11] + w[13] - w[14]) * inv;

    coeffs[n] = make_float4(C0, Ca, Cb, Cab);
}

// ---------------------------------------------------------------------------
// Kernel B: out[r,n] = C0 + Ca*a + Cb*b + Cab*a*b,  a=x[r,i0], b=x[r,i1].
//  - CHUNK=4096 neurons per block, 16 per thread, grouped 4-consecutive for
//    float4 stores.
//  - One 32 KiB x-row staged in LDS per row iteration; next row prefetched
//    into registers during gather/compute (hides L2 latency).
//  - 1D grid + XCD swizzle: 8 chunk-blocks x 16 row-groups per XCD keeps that
//    XCD's x working set (2 MiB) resident in its 4 MiB L2.
// ---------------------------------------------------------------------------
constexpr int CHUNK  = 4096;             // neurons per block
constexpr int NPT    = CHUNK / 256;      // 16 neurons per thread (4 groups of 4)
constexpr int NGRP   = NPT / 4;          // 4 float4-store groups
constexpr int ROWS_PER_BLOCK = 4;
constexpr int XF4    = INPUT_SIZE / 4 / 256;  // 8 float4 stage loads per thread
constexpr int NCHUNKS = NUM_NEURONS / CHUNK;         // 8
constexpr int NROWG   = BATCH / ROWS_PER_BLOCK;      // 128
constexpr int NXCD    = 8;

__global__ __launch_bounds__(256) void logic_main_kernel(
    const float*  __restrict__ x,
    const float4* __restrict__ coeffs,
    const int4*   __restrict__ idx4,     // (NUM_NEURONS/2) int4 = pairs of int2
    float4*       __restrict__ out4)
{
    __shared__ float sx[INPUT_SIZE];     // 32 KiB

    const int tid = threadIdx.x;

    // ---- XCD-aware swizzle of the 1D grid (1024 blocks, round-robin->XCD).
    // xcd = bid % 8 owns row-groups [xcd*16, xcd*16+16) x all 8 chunks.
    const int bid    = blockIdx.x;
    const int xcd    = bid % NXCD;
    const int within = bid / NXCD;               // 0..127
    const int chunkI = within % NCHUNKS;         // 0..7
    const int rowgI  = xcd * (NROWG / NXCD) + within / NCHUNKS;  // 0..127
    const int chunk0 = chunkI * CHUNK;
    const int row0   = rowgI * ROWS_PER_BLOCK;

    // ---- Per-thread neuron state: group g covers neurons
    //      n = chunk0 + g*1024 + tid*4 + j,  j=0..3
    float4 c[NPT];
    int2   id[NPT];
#pragma unroll
    for (int g = 0; g < NGRP; ++g) {
        const int nbase = chunk0 + g * 1024 + tid * 4;
#pragma unroll
        for (int j = 0; j < 4; ++j) c[g*4+j] = coeffs[nbase + j];
        // two int4 loads give 4 neurons' (i0,i1) pairs
        const int4 p0 = idx4[(nbase >> 1) + 0];
        const int4 p1 = idx4[(nbase >> 1) + 1];
        id[g*4+0] = make_int2(p0.x, p0.y);
        id[g*4+1] = make_int2(p0.z, p0.w);
        id[g*4+2] = make_int2(p1.x, p1.y);
        id[g*4+3] = make_int2(p1.z, p1.w);
    }

    // ---- Prefetch row0 into registers.
    float4 pf[XF4];
    {
        const float4* xr = reinterpret_cast<const float4*>(x + (size_t)row0 * INPUT_SIZE);
#pragma unroll
        for (int i = 0; i < XF4; ++i) pf[i] = xr[i * 256 + tid];
    }

    float4* s4 = reinterpret_cast<float4*>(sx);

    for (int r = 0; r < ROWS_PER_BLOCK; ++r) {
        const int row = row0 + r;
        if (r) __syncthreads();          // previous row's gathers complete

        // Stage prefetched row into LDS.
#pragma unroll
        for (int i = 0; i < XF4; ++i) s4[i * 256 + tid] = pf[i];
        __syncthreads();

        // Prefetch next row while we gather from LDS.
        if (r + 1 < ROWS_PER_BLOCK) {
            const float4* xr = reinterpret_cast<const float4*>(x + (size_t)(row + 1) * INPUT_SIZE);
#pragma unroll
            for (int i = 0; i < XF4; ++i) pf[i] = xr[i * 256 + tid];
        }

        // Gather + affine eval + vectorized store.
        float4* o = out4 + ((size_t)row * NUM_NEURONS + chunk0) / 4;
#pragma unroll
        for (int g = 0; g < NGRP; ++g) {
            float res[4];
#pragma unroll
            for (int j = 0; j < 4; ++j) {
                const float4 cc = c[g*4+j];
                const float a = sx[id[g*4+j].x];
                const float b = sx[id[g*4+j].y];
                res[j] = fmaf(a, fmaf(cc.w, b, cc.y), fmaf(cc.z, b, cc.x));
            }
            o[g * 256 + tid] = make_float4(res[0], res[1], res[2], res[3]);
        }
    }
}

extern "C" void kernel_launch(void* const* d_in, const int* in_sizes, int n_in,
                              void* d_out, int out_size, void* d_ws, size_t ws_size,
                              hipStream_t stream)
{
    const float* x   = (const float*)d_in[0];   // (512, 8192) f32
    const float* gw  = (const float*)d_in[1];   // (32768, 16) f32
    const int4*  idx = (const int4*)d_in[2];    // (32768, 2) i32, read as int4 pairs
    float4* out = (float4*)d_out;               // (512, 32768) f32

    float4* coeffs = (float4*)d_ws;             // 512 KiB scratch

    logic_coeff_kernel<<<NUM_NEURONS / 256, 256, 0, stream>>>(gw, coeffs);

    const int nblocks = NCHUNKS * NROWG;        // 1024
    logic_main_kernel<<<nblocks, 256, 0, stream>>>(x, coeffs, idx, out);
}

// Round 4
// 109.798 us; speedup vs baseline: 1.4014x; 1.4014x over previous
//
#include <hip/hip_runtime.h>
#include <hip/hip_bf16.h>

// Problem constants (from reference)
#define NUM_NEURONS 32768
#define INPUT_SIZE  8192
#define BATCH       512

typedef float f32x4 __attribute__((ext_vector_type(4)));

// ---------------------------------------------------------------------------
// Kernel A: per-neuron softmax over 16 gate weights -> 4 affine coefficients.
// Every logic op is affine in {1, a, b, ab}: out = C0 + Ca*a + Cb*b + Cab*a*b
// ---------------------------------------------------------------------------
__global__ __launch_bounds__(256) void logic_coeff_kernel(
    const float* __restrict__ gw, float4* __restrict__ coeffs)
{
    const int n = blockIdx.x * 256 + threadIdx.x;
    if (n >= NUM_NEURONS) return;
    const float* g = gw + (size_t)n * 16;

    float w[16];
#pragma unroll
    for (int i = 0; i < 16; i += 4) {
        float4 v = *reinterpret_cast<const float4*>(g + i);
        w[i+0] = v.x; w[i+1] = v.y; w[i+2] = v.z; w[i+3] = v.w;
    }
    float m = w[0];
#pragma unroll
    for (int i = 1; i < 16; ++i) m = fmaxf(m, w[i]);
    float s = 0.f;
#pragma unroll
    for (int i = 0; i < 16; ++i) { w[i] = expf(w[i] - m); s += w[i]; }
    const float inv = 1.0f / s;

    const float C0  = (w[8] + w[9] + w[10] + w[11] + w[12] + w[13] + w[14] + w[15]) * inv;
    const float Ca  = (w[2] + w[3] + w[6] + w[7] - w[8] - w[9] - w[12] - w[13]) * inv;
    const float Cb  = (w[4] + w[5] + w[6] + w[7] - w[8] - w[9] - w[10] - w[11]) * inv;
    const float Cab = (w[1] - w[2] - w[4] - 2.f*w[6] - w[7]
                       + w[8] + 2.f*w[9] + w[11] + w[13] - w[14]) * inv;

    coeffs[n] = make_float4(C0, Ca, Cb, Cab);
}

// ---------------------------------------------------------------------------
// Kernel B: out[r,n] = C0 + Ca*a + Cb*b + Cab*a*b,  a=x[r,i0], b=x[r,i1].
//  - CHUNK=2048 neurons/block (8/thread = 48 VGPRs of state -> NO spill).
//  - ROWS_PER_BLOCK=8 rows/block amortize the register-held coeffs.
//  - x row staged via global_load_lds width=16 (no VGPR round-trip).
//  - XCD swizzle: each XCD owns 8 row-groups x all 16 chunks -> 2 MiB x
//    working set resident in its private 4 MiB L2.
//  - Nontemporal float4 output stores (output never re-read; keep L2 for x).
// ---------------------------------------------------------------------------
constexpr int CHUNK  = 2048;                  // neurons per block
constexpr int NPT    = CHUNK / 256;           // 8 per thread
constexpr int NGRP   = NPT / 4;               // 2 float4-store groups
constexpr int ROWS_PER_BLOCK = 8;
constexpr int XF4    = INPUT_SIZE / 4 / 256;  // 8 stage iterations
constexpr int NCHUNKS = NUM_NEURONS / CHUNK;          // 16
constexpr int NROWG   = BATCH / ROWS_PER_BLOCK;       // 64
constexpr int NXCD    = 8;

__global__ __launch_bounds__(256, 4) void logic_main_kernel(
    const float*  __restrict__ x,
    const float4* __restrict__ coeffs,
    const int4*   __restrict__ idx4,
    float*        __restrict__ out)
{
    __shared__ float sx[INPUT_SIZE];          // 32 KiB

    const int tid = threadIdx.x;

    // XCD-aware swizzle: bid%8 = native XCD round-robin.
    const int bid    = blockIdx.x;
    const int xcd    = bid % NXCD;
    const int within = bid / NXCD;                        // 0..127
    const int chunkI = within % NCHUNKS;                  // 0..15
    const int rowgI  = xcd * (NROWG / NXCD) + within / NCHUNKS;  // 0..63
    const int chunk0 = chunkI * CHUNK;
    const int row0   = rowgI * ROWS_PER_BLOCK;

    // Per-thread neuron state (registers): group g covers
    //   n = chunk0 + g*1024 + tid*4 + j, j=0..3
    float4 c[NPT];
    int2   id[NPT];
#pragma unroll
    for (int g = 0; g < NGRP; ++g) {
        const int nbase = chunk0 + g * 1024 + tid * 4;
#pragma unroll
        for (int j = 0; j < 4; ++j) c[g*4+j] = coeffs[nbase + j];
        const int4 p0 = idx4[(nbase >> 1) + 0];
        const int4 p1 = idx4[(nbase >> 1) + 1];
        id[g*4+0] = make_int2(p0.x, p0.y);
        id[g*4+1] = make_int2(p0.z, p0.w);
        id[g*4+2] = make_int2(p1.x, p1.y);
        id[g*4+3] = make_int2(p1.z, p1.w);
    }

    float4* s4 = reinterpret_cast<float4*>(sx);

    for (int r = 0; r < ROWS_PER_BLOCK; ++r) {
        const int row = row0 + r;
        if (r) __syncthreads();               // prev row's gathers complete

        // Async global->LDS staging, 16 B/lane, linear layout.
        const float4* xrow = reinterpret_cast<const float4*>(x + (size_t)row * INPUT_SIZE);
#pragma unroll
        for (int i = 0; i < XF4; ++i) {
            __builtin_amdgcn_global_load_lds(
                (const __attribute__((address_space(1))) void*)(xrow + i * 256 + tid),
                (__attribute__((address_space(3))) void*)(s4 + i * 256 + tid),
                16, 0, 0);
        }
        __syncthreads();                      // vmcnt(0) drained by barrier

        // Gather + affine eval + nontemporal float4 store.
        f32x4* o = reinterpret_cast<f32x4*>(out + (size_t)row * NUM_NEURONS + chunk0) ;
#pragma unroll
        for (int g = 0; g < NGRP; ++g) {
            f32x4 res;
#pragma unroll
            for (int j = 0; j < 4; ++j) {
                const float4 cc = c[g*4+j];
                const float a = sx[id[g*4+j].x];
                const float b = sx[id[g*4+j].y];
                res[j] = fmaf(a, fmaf(cc.w, b, cc.y), fmaf(cc.z, b, cc.x));
            }
            __builtin_nontemporal_store(res, o + g * 256 + tid);
        }
    }
}

extern "C" void kernel_launch(void* const* d_in, const int* in_sizes, int n_in,
                              void* d_out, int out_size, void* d_ws, size_t ws_size,
                              hipStream_t stream)
{
    const float* x   = (const float*)d_in[0];   // (512, 8192) f32
    const float* gw  = (const float*)d_in[1];   // (32768, 16) f32
    const int4*  idx = (const int4*)d_in[2];    // (32768, 2) i32, int4 pairs
    float* out = (float*)d_out;                 // (512, 32768) f32

    float4* coeffs = (float4*)d_ws;             // 512 KiB scratch

    logic_coeff_kernel<<<NUM_NEURONS / 256, 256, 0, stream>>>(gw, coeffs);

    const int nblocks = NCHUNKS * NROWG;        // 1024
    logic_main_kernel<<<nblocks, 256, 0, stream>>>(x, coeffs, idx, out);
}